// Round 7
// baseline (109.038 us; speedup 1.0000x reference)
//
#include <hip/hip_runtime.h>

// CLRNetIoULoss: pred/target (NL, 72) fp32 -> scalar fp32 loss.
// R7 = R6 + packed single-u32 LDS partials (halves LDS: 18.4KB -> 9.2KB,
// 7 -> 8 blocks/CU, 32 waves/CU; halves LDS traffic).
// Pack per pair: bits[0:19] = round(D * 2^16) (D < 8), [20:23] = tp, [24:27] = er.
// Phase 2 accumulates D in fixed point (quant err ~7e-5 << 3.56e-2 threshold).
// so = 2W*tp - D ; su = 2W*tp + D.

#define NR    72
#define NP2   9                // float4-PAIRS per row
#define BLOCK 256
#define RPB   256              // rows per block
#define P2PB  (RPB * NP2)      // 2304 pairs per array per block

__device__ __forceinline__ void accum_pair(const char* pred, const char* tgt,
                                           unsigned off, float& d, int& tp,
                                           int& er) {
  float4 p0 = *(const float4*)(pred + off);
  float4 p1 = *(const float4*)(pred + off + 16);
  float4 t0 = *(const float4*)(tgt + off);
  float4 t1 = *(const float4*)(tgt + off + 16);
#pragma unroll
  for (int j = 0; j < 4; ++j) {
    float pv = (&p0.x)[j], tv = (&t0.x)[j];
    bool vp = (pv >= 0.0f) & (pv < 1.0f);
    bool vt = (tv >= 0.0f) & (tv < 1.0f);
    bool both = vp & vt;
    d += both ? fabsf(pv - tv) : 0.0f;
    tp += both ? 1 : 0;
    er += (vp != vt) ? 1 : 0;
  }
#pragma unroll
  for (int j = 0; j < 4; ++j) {
    float pv = (&p1.x)[j], tv = (&t1.x)[j];
    bool vp = (pv >= 0.0f) & (pv < 1.0f);
    bool vt = (tv >= 0.0f) & (tv < 1.0f);
    bool both = vp & vt;
    d += both ? fabsf(pv - tv) : 0.0f;
    tp += both ? 1 : 0;
    er += (vp != vt) ? 1 : 0;
  }
}

__global__ __launch_bounds__(BLOCK, 8) void clrnet_iou_rows(
    const char* __restrict__ pred,
    const char* __restrict__ tgt,
    float* __restrict__ partial,   // one float per block
    int nl) {
  __shared__ unsigned sp_[P2PB];  // packed per-pair partial
  __shared__ float ws[BLOCK / 64];

  const unsigned base_b = (unsigned)blockIdx.x * (P2PB * 32u); // byte offset
  const bool full = ((int)blockIdx.x != (int)gridDim.x - 1);   // uniform

  // ---- Phase 1: coalesced global (32B/lane) -> packed partials in LDS ----
  if (full) {
#pragma unroll
    for (int k = 0; k < NP2; ++k) {
      const int iloc = k * BLOCK + threadIdx.x;        // 0..2303, linear
      const unsigned off = base_b + (unsigned)iloc * 32u;
      float d = 0.0f;
      int tp = 0, er = 0;
      accum_pair(pred, tgt, off, d, tp, er);
      const unsigned df = (unsigned)__float2int_rn(d * 65536.0f);
      sp_[iloc] = df | ((unsigned)tp << 20) | ((unsigned)er << 24);
    }
  } else {
    const int tail_pairs = nl * NP2 - (int)blockIdx.x * P2PB;
#pragma unroll
    for (int k = 0; k < NP2; ++k) {
      const int iloc = k * BLOCK + threadIdx.x;
      float d = 0.0f;
      int tp = 0, er = 0;
      if (iloc < tail_pairs) {
        const unsigned off = base_b + (unsigned)iloc * 32u;
        accum_pair(pred, tgt, off, d, tp, er);
      }
      const unsigned df = (unsigned)__float2int_rn(d * 65536.0f);
      sp_[iloc] = df | ((unsigned)tp << 20) | ((unsigned)er << 24);
    }
  }
  __syncthreads();

  // ---- Phase 2: one thread per row, nonlinear part ----
  float loss = 0.0f;
  const int row = (int)blockIdx.x * RPB + (int)threadIdx.x;
  if (row < nl) {
    int Df = 0, tp = 0, er = 0;
    const int rbase = threadIdx.x * NP2;   // stride 9 dwords: gcd(9,32)=1
#pragma unroll
    for (int j = 0; j < NP2; ++j) {
      const unsigned v = sp_[rbase + j];
      Df += (int)(v & 0xFFFFFu);
      tp += (int)((v >> 20) & 0xFu);
      er += (int)(v >> 24);
    }
    const float D = (float)Df * (1.0f / 65536.0f);
    const float W2 = 2.0f * (15.0f / 800.0f);
    const float ftp = (float)tp;
    float so = W2 * ftp - D;
    float su = W2 * ftp + D;
    float iou = so / (su + 1e-9f);
    if (tp > er && er > 0) {
      iou *= (1.0f - (float)er / (ftp + 1e-9f));
    }
    loss = 1.0f - iou;
  }

  // ---- block reduce of loss ----
#pragma unroll
  for (int off = 32; off > 0; off >>= 1)
    loss += __shfl_down(loss, off, 64);

  const int lane = threadIdx.x & 63;
  const int wid  = threadIdx.x >> 6;
  if (lane == 0) ws[wid] = loss;
  __syncthreads();
  if (threadIdx.x == 0) {
    float s = 0.0f;
#pragma unroll
    for (int w = 0; w < BLOCK / 64; ++w) s += ws[w];
    partial[blockIdx.x] = s;
  }
}

__global__ __launch_bounds__(256) void clrnet_iou_finish(
    const float* __restrict__ partial, int nparts, float* __restrict__ out,
    float inv_nl) {
  // single block; fp64 accumulation for deterministic, accurate final sum
  double acc = 0.0;
  for (int i = threadIdx.x; i < nparts; i += 256)
    acc += (double)partial[i];

  __shared__ double sd[256];
  sd[threadIdx.x] = acc;
  __syncthreads();
#pragma unroll
  for (int s = 128; s > 0; s >>= 1) {
    if (threadIdx.x < s) sd[threadIdx.x] += sd[threadIdx.x + s];
    __syncthreads();
  }
  if (threadIdx.x == 0) {
    const double LOSS_WEIGHT = 1.0;
    out[0] = (float)(sd[0] * (double)inv_nl * LOSS_WEIGHT);
  }
}

extern "C" void kernel_launch(void* const* d_in, const int* in_sizes, int n_in,
                              void* d_out, int out_size, void* d_ws, size_t ws_size,
                              hipStream_t stream) {
  const char* pred = (const char*)d_in[0];
  const char* tgt  = (const char*)d_in[1];
  float* out = (float*)d_out;

  const int nl = in_sizes[0] / NR;               // 1,000,000
  const int nblocks = (nl + RPB - 1) / RPB;      // 3907

  float* partial = (float*)d_ws;                 // nblocks floats of scratch

  clrnet_iou_rows<<<nblocks, BLOCK, 0, stream>>>(pred, tgt, partial, nl);
  clrnet_iou_finish<<<1, 256, 0, stream>>>(partial, nblocks, out,
                                           1.0f / (float)nl);
}